// Round 2
// baseline (465.912 us; speedup 1.0000x reference)
//
#include <hip/hip_runtime.h>

#define NUM_HEADS 16
#define HEAD_DIM 128
#define KV_BLOCK 16          // tokens per physical KV block
#define BATCH 16
#define BLOCKS_PER_SEQ 128
#define MAX_CTX 2048
#define PART_TOKENS 256      // tokens per partition (16 KV blocks)
#define NUM_PARTS (MAX_CTX / PART_TOKENS)   // 8
#define WS_STRIDE (HEAD_DIM + 2)            // per-partition: 128 floats O, m, l
#define NEG_BIG -1e30f
#define TOKEN_STRIDE (NUM_HEADS * HEAD_DIM) // 2048 floats = 8 KB per token row

// Kernel 1: one block per (batch, head, partition). 256 threads = 8 half-waves.
// Single-pass online softmax: each half-wave (32 lanes x float4 = one 512 B row)
// streams its 32 tokens, loading K and V together with one-iteration register
// prefetch (4 outstanding dwordx4 per wave). Partials merged via LDS at the end.
__global__ __launch_bounds__(256) void paged_attn_partial(
    const float* __restrict__ q,            // [B, H, D]
    const float* __restrict__ kcache,       // [NB, KV_BLOCK, H, D]
    const float* __restrict__ vcache,       // [NB, KV_BLOCK, H, D]
    const int*   __restrict__ block_tables, // [B, BLOCKS_PER_SEQ]
    const int*   __restrict__ ctx_lens,     // [B]
    float* __restrict__ ws)                 // [B*H*NUM_PARTS, WS_STRIDE]
{
    const int part = blockIdx.x;
    const int h    = blockIdx.y;
    const int b    = blockIdx.z;
    const int tid  = threadIdx.x;

    float* wsp = ws + ((size_t)((b * NUM_HEADS + h) * NUM_PARTS + part)) * WS_STRIDE;

    const int ctx = ctx_lens[b];
    int valid_n = ctx - part * PART_TOKENS;
    if (valid_n > PART_TOKENS) valid_n = PART_TOKENS;

    if (valid_n <= 0) {
        if (tid < HEAD_DIM) wsp[tid] = 0.0f;
        if (tid == 0) { wsp[HEAD_DIM] = NEG_BIG; wsp[HEAD_DIM + 1] = 0.0f; }
        return;
    }

    __shared__ __align__(16) float sQ[HEAD_DIM];
    __shared__ int   sBlocks[PART_TOKENS / KV_BLOCK];   // 16 physical block ids
    __shared__ __align__(16) float sAcc[8][HEAD_DIM];   // per-half-wave partials
    __shared__ float sM[8], sL[8];

    if (tid < HEAD_DIM)
        sQ[tid] = q[((size_t)b * NUM_HEADS + h) * HEAD_DIM + tid] * 0.088388347648318447f; // *1/sqrt(128)
    if (tid < PART_TOKENS / KV_BLOCK)
        sBlocks[tid] = block_tables[b * BLOCKS_PER_SEQ + part * (PART_TOKENS / KV_BLOCK) + tid];
    __syncthreads();

    const int hw     = tid >> 5;   // half-wave 0..7, one token per iteration
    const int lane32 = tid & 31;
    const float4 q4 = *(const float4*)(&sQ[lane32 * 4]);  // pre-scaled

    const int head_lane_off = h * HEAD_DIM + lane32 * 4;

    float m = NEG_BIG, l = 0.f;
    float4 acc = make_float4(0.f, 0.f, 0.f, 0.f);

    // 32-bit element offsets: max 2047*32768 + 32767 < 2^27, safe.
    float4 k4, v4;
    if (hw < valid_n) {
        const int o = sBlocks[hw >> 4] * (KV_BLOCK * TOKEN_STRIDE)
                    + (hw & 15) * TOKEN_STRIDE + head_lane_off;
        k4 = *(const float4*)(kcache + o);
        v4 = *(const float4*)(vcache + o);
    }

    for (int t = hw; t < valid_n; t += 8) {
        const float4 ck = k4;
        const float4 cv = v4;
        const int tn = t + 8;
        if (tn < valid_n) {      // prefetch next token's K and V
            const int o = sBlocks[tn >> 4] * (KV_BLOCK * TOKEN_STRIDE)
                        + (tn & 15) * TOKEN_STRIDE + head_lane_off;
            k4 = *(const float4*)(kcache + o);
            v4 = *(const float4*)(vcache + o);
        }

        float d = ck.x * q4.x + ck.y * q4.y + ck.z * q4.z + ck.w * q4.w;
        #pragma unroll
        for (int off = 1; off < 32; off <<= 1)
            d += __shfl_xor(d, off, 64);     // xor<32 stays inside the half-wave

        const float mnew  = fmaxf(m, d);
        const float alpha = __expf(m - mnew);  // first iter: exp(-1e30-..) -> 0
        const float p     = __expf(d - mnew);
        l = l * alpha + p;
        acc.x = acc.x * alpha + p * cv.x;
        acc.y = acc.y * alpha + p * cv.y;
        acc.z = acc.z * alpha + p * cv.z;
        acc.w = acc.w * alpha + p * cv.w;
        m = mnew;
    }

    *(float4*)(&sAcc[hw][lane32 * 4]) = acc;
    if (lane32 == 0) { sM[hw] = m; sL[hw] = l; }
    __syncthreads();

    // Merge the 8 half-wave partials (threads 0..127, one per output element).
    if (tid < HEAD_DIM) {
        float M = NEG_BIG;
        #pragma unroll
        for (int g = 0; g < 8; ++g) M = fmaxf(M, sM[g]);
        float o = 0.f, L = 0.f;
        #pragma unroll
        for (int g = 0; g < 8; ++g) {
            const float w = __expf(sM[g] - M);   // empty half-wave: exp(-1e30-M)=0
            o += w * sAcc[g][tid];
            L += w * sL[g];
        }
        wsp[tid] = o;                            // unnormalized (post exp(.-M))
        if (tid == 0) { wsp[HEAD_DIM] = M; wsp[HEAD_DIM + 1] = L; }
    }
}

// Kernel 2: combine NUM_PARTS partials per (b,h) with log-sum-exp merge.
__global__ __launch_bounds__(128) void paged_attn_reduce(
    const float* __restrict__ ws,
    float* __restrict__ out)   // [B, H, D]
{
    const int bh  = blockIdx.x;          // 0..B*H-1
    const int tid = threadIdx.x;         // 0..127
    const float* base = ws + (size_t)bh * NUM_PARTS * WS_STRIDE;

    __shared__ float sM[NUM_PARTS], sL[NUM_PARTS];
    if (tid < NUM_PARTS) {
        sM[tid] = base[tid * WS_STRIDE + HEAD_DIM];
        sL[tid] = base[tid * WS_STRIDE + HEAD_DIM + 1];
    }
    __syncthreads();

    float M = NEG_BIG;
    #pragma unroll
    for (int p = 0; p < NUM_PARTS; ++p) M = fmaxf(M, sM[p]);

    float w[NUM_PARTS];
    float L = 0.f;
    #pragma unroll
    for (int p = 0; p < NUM_PARTS; ++p) {
        const float wi = (sL[p] > 0.f) ? __expf(sM[p] - M) : 0.f;
        w[p] = wi;
        L += wi * sL[p];
    }

    float o = 0.f;
    #pragma unroll
    for (int p = 0; p < NUM_PARTS; ++p)
        o += w[p] * base[p * WS_STRIDE + tid];

    out[(size_t)bh * HEAD_DIM + tid] = o / L;
}

extern "C" void kernel_launch(void* const* d_in, const int* in_sizes, int n_in,
                              void* d_out, int out_size, void* d_ws, size_t ws_size,
                              hipStream_t stream) {
    const float* q  = (const float*)d_in[0];
    const float* k  = (const float*)d_in[1];
    const float* v  = (const float*)d_in[2];
    const int*   bt = (const int*)d_in[3];
    const int*   cl = (const int*)d_in[4];
    float* out = (float*)d_out;
    float* ws  = (float*)d_ws;   // needs 256*8*130*4 = ~1.02 MB

    dim3 grid1(NUM_PARTS, NUM_HEADS, BATCH);
    paged_attn_partial<<<grid1, 256, 0, stream>>>(q, k, v, bt, cl, ws);

    dim3 grid2(BATCH * NUM_HEADS);
    paged_attn_reduce<<<grid2, 128, 0, stream>>>(ws, out);
}